// Round 1
// baseline (454.523 us; speedup 1.0000x reference)
//
#include <hip/hip_runtime.h>

typedef __bf16 bf16_t;
typedef __bf16 bf16x8 __attribute__((ext_vector_type(8)));
typedef float f32x4 __attribute__((ext_vector_type(4)));
typedef unsigned int u32x4 __attribute__((ext_vector_type(4)));

#define KDIM 512
#define NDIM 512
#define BM 128
#define BN 128
#define BK 32
#define NSTEP (KDIM / BK)  // 16

// async 16B global->LDS. LDS dest must be wave-uniform base; HW scatters lane*16.
__device__ __forceinline__ void gld_lds16(const float* g, float* lds_uniform) {
  __builtin_amdgcn_global_load_lds(
      (const __attribute__((address_space(1))) void*)g,
      (__attribute__((address_space(3))) void*)lds_uniform, 16, 0, 0);
}

__device__ __forceinline__ bf16x8 neg8(bf16x8 v) {
  union { bf16x8 b; u32x4 u; } x;
  x.b = v;
  x.u = x.u ^ 0x80008000u;  // flip bf16 sign bits (packed)
  return x.b;
}

// Read one A fragment (8 fp32 along k) from the granule-swizzled fp32 LDS tile
// and convert to bf16x8. Tile layout: slot(row, g') holds global granule
// g = g' ^ (row & 7); granule = 4 floats = 16 B. 2-way bank alias only (free).
__device__ __forceinline__ bf16x8 afrag(const float* ldsx, int r, int h4) {
  const int base = r * 8;
  const int sw = r & 7;
  const float4 a = *(const float4*)(ldsx + 4 * (base + ((2 * h4) ^ sw)));
  const float4 b = *(const float4*)(ldsx + 4 * (base + ((2 * h4 + 1) ^ sw)));
  bf16x8 f;
  f[0] = (__bf16)a.x; f[1] = (__bf16)a.y; f[2] = (__bf16)a.z; f[3] = (__bf16)a.w;
  f[4] = (__bf16)b.x; f[5] = (__bf16)b.y; f[6] = (__bf16)b.z; f[7] = (__bf16)b.w;
  return f;
}

__device__ __forceinline__ bf16x8 pack8(float4 a, float4 b) {
  bf16x8 f;
  f[0] = (__bf16)a.x; f[1] = (__bf16)a.y; f[2] = (__bf16)a.z; f[3] = (__bf16)a.w;
  f[4] = (__bf16)b.x; f[5] = (__bf16)b.y; f[6] = (__bf16)b.z; f[7] = (__bf16)b.w;
  return f;
}

struct Wregs { float4 r0, r1, i0, i1, r2, r3, i2, i3; };  // 32 VGPRs

// 2-phase counted-vmcnt pipeline:
//   x tiles: double-buffered LDS, staged by global_load_lds DMA (8 ops/thread/step)
//   W tiles: single LDS buffer + register prefetch (8 float4 loads issued BEFORE
//            the x DMAs so the compiler's wait for them is vmcnt(8), keeping the
//            x DMAs in flight); cvt+ds_write lands between the two barriers.
// Steady-state invariant at each step entry: outstanding VMEM (oldest->newest)
//   = [W(t+1):8][x(t+1):8]. In-loop manual wait is vmcnt(16): retires exactly
//   x(t+1) while leaving W(t+2)+x(t+2) (issued this step) in flight. vmcnt never
//   drains to 0 in the main loop (T4).
__global__ __launch_bounds__(256, 2) void dft_cgemm_kernel(
    const float* __restrict__ xr, const float* __restrict__ xi,
    const float* __restrict__ wre, const float* __restrict__ wim,
    float* __restrict__ out) {
  __shared__ __align__(16) float  lds_x[2][2][BM * BK];  // [kbuf][re/im], 64 KB
  __shared__ __align__(16) bf16_t lds_w[2][BN * BK];     // [re/im], 16 KB, fragment-ordered

  const int t = threadIdx.x;
  const int lane = t & 63;
  const int wv = t >> 6;  // wave 0..3

  // XCD-aware swizzle: xcd = b&7 owns m-tiles [32*xcd, 32*xcd+32) x all 4 n-tiles.
  const int b = blockIdx.x;  // 0..1023
  const int xcd = b & 7;
  const int sidx = b >> 3;   // 0..127
  const int m0 = (xcd * 32 + (sidx >> 2)) * BM;
  const int n0 = (sidx & 3) * BN;

  // wave tile: 64x64; 2x2 wave grid over the 128x128 block tile
  const int wm = (wv >> 1) * 64;
  const int wn = (wv & 1) * 64;
  const int l16 = lane & 15;
  const int h4 = lane >> 4;
  const int wt15 = t & 15;
  const int wg = (t >> 4) & 3;

  f32x4 acc_re[4][4], acc_im[4][4];
#pragma unroll
  for (int i = 0; i < 4; ++i)
#pragma unroll
    for (int j = 0; j < 4; ++j) {
      acc_re[i][j] = (f32x4){0.f, 0.f, 0.f, 0.f};
      acc_im[i][j] = (f32x4){0.f, 0.f, 0.f, 0.f};
    }

  // ---- stage x (fp32, async DMA, granule-swizzled global addresses) ----
  auto stage_x = [&](int buf, int step) {
    const int k0 = step * BK;
#pragma unroll
    for (int it = 0; it < 4; ++it) {
      const int S = it * 256 + t;         // granule slot 0..1023
      const int row = S >> 3;
      const int g = (S & 7) ^ (row & 7);  // global granule for this slot
      const size_t goff = (size_t)(m0 + row) * KDIM + k0 + g * 4;
      float* dr = &lds_x[buf][0][0] + 4 * (it * 256 + wv * 64);  // wave-uniform base
      float* di = &lds_x[buf][1][0] + 4 * (it * 256 + wv * 64);
      gld_lds16(xr + goff, dr);
      gld_lds16(xi + goff, di);
    }
  };

  // ---- W prefetch: 8 float4 global loads into registers ----
  auto load_w = [&](int step) {
    Wregs W;
    const int k0 = step * BK;
    const int row0 = wv * 16 + wt15;
    const float* gr0 = wre + (size_t)(n0 + row0) * KDIM + k0 + wg * 8;
    const float* gi0 = wim + (size_t)(n0 + row0) * KDIM + k0 + wg * 8;
    W.r0 = ((const float4*)gr0)[0]; W.r1 = ((const float4*)gr0)[1];
    W.i0 = ((const float4*)gi0)[0]; W.i1 = ((const float4*)gi0)[1];
    const int row1 = 64 + wv * 16 + wt15;
    const float* gr1 = wre + (size_t)(n0 + row1) * KDIM + k0 + wg * 8;
    const float* gi1 = wim + (size_t)(n0 + row1) * KDIM + k0 + wg * 8;
    W.r2 = ((const float4*)gr1)[0]; W.r3 = ((const float4*)gr1)[1];
    W.i2 = ((const float4*)gi1)[0]; W.i3 = ((const float4*)gi1)[1];
    return W;
  };

  // ---- cvt + ds_write W into fragment-ordered LDS (wave-contiguous slots) ----
  auto write_w = [&](const Wregs& W) {
    *(bf16x8*)(&lds_w[0][0] + (size_t)t * 8)         = pack8(W.r0, W.r1);
    *(bf16x8*)(&lds_w[1][0] + (size_t)t * 8)         = pack8(W.i0, W.i1);
    *(bf16x8*)(&lds_w[0][0] + (size_t)(256 + t) * 8) = pack8(W.r2, W.r3);
    *(bf16x8*)(&lds_w[1][0] + (size_t)(256 + t) * 8) = pack8(W.i2, W.i3);
  };

  // ---- fragments + 4 MFMA streams for one K-step ----
  auto compute = [&](int buf) {
    const float* ldsxr = &lds_x[buf][0][0];
    const float* ldsxi = &lds_x[buf][1][0];
    bf16x8 ar[4], ai[4], br[4], bi[4], nbi[4];
#pragma unroll
    for (int mi = 0; mi < 4; ++mi) {
      const int r = wm + mi * 16 + l16;
      ar[mi] = afrag(ldsxr, r, h4);
      ai[mi] = afrag(ldsxi, r, h4);
    }
#pragma unroll
    for (int ni = 0; ni < 4; ++ni) {
      const int slot = ((wn >> 4) + ni) * 64 + h4 * 16 + l16;
      br[ni] = *(const bf16x8*)(&lds_w[0][0] + slot * 8);
      bi[ni] = *(const bf16x8*)(&lds_w[1][0] + slot * 8);
      nbi[ni] = neg8(bi[ni]);
    }
    // re += xr*wr - xi*wi ; im += xr*wi + xi*wr
#pragma unroll
    for (int mi = 0; mi < 4; ++mi) {
#pragma unroll
      for (int ni = 0; ni < 4; ++ni) {
        acc_re[mi][ni] = __builtin_amdgcn_mfma_f32_16x16x32_bf16(ar[mi], br[ni], acc_re[mi][ni], 0, 0, 0);
        acc_im[mi][ni] = __builtin_amdgcn_mfma_f32_16x16x32_bf16(ar[mi], bi[ni], acc_im[mi][ni], 0, 0, 0);
        acc_re[mi][ni] = __builtin_amdgcn_mfma_f32_16x16x32_bf16(ai[mi], nbi[ni], acc_re[mi][ni], 0, 0, 0);
        acc_im[mi][ni] = __builtin_amdgcn_mfma_f32_16x16x32_bf16(ai[mi], br[ni], acc_im[mi][ni], 0, 0, 0);
      }
    }
  };

  // ---------------- prologue ----------------
  Wregs Wp = load_w(0);   // W(0):8
  stage_x(0, 0);          // + x(0):8
  write_w(Wp);            // compiler waits vmcnt(8) for W(0); x(0) stays in flight
  Wp = load_w(1);         // + W(1):8
  stage_x(1, 1);          // + x(1):8
  asm volatile("s_waitcnt vmcnt(16)" ::: "memory");   // x(0) complete
  asm volatile("s_waitcnt lgkmcnt(0)" ::: "memory");  // W(0) ds_write committed
  __builtin_amdgcn_s_barrier();
  __builtin_amdgcn_sched_barrier(0);

  // ---------------- main loop: compute t=0..13, prefetch t+2 ----------------
#pragma unroll 1
  for (int tt = 0; tt < NSTEP - 2; tt += 2) {
    // even step: compute t=tt from buf0
    compute(0);
    __builtin_amdgcn_s_barrier();            // all waves done reading lds_w(t), lds_x[0]
    __builtin_amdgcn_sched_barrier(0);
    write_w(Wp);                             // W(t+1) -> lds_w  [compiler: vmcnt(8)]
    Wp = load_w(tt + 2);                     // issue W(t+2) BEFORE x(t+2) DMAs
    stage_x(0, tt + 2);                      // x(t+2) -> buf0 (just-read buffer)
    asm volatile("s_waitcnt vmcnt(16)" ::: "memory");   // retire x(t+1); keep 16 in flight
    asm volatile("s_waitcnt lgkmcnt(0)" ::: "memory");  // W(t+1) write visible
    __builtin_amdgcn_s_barrier();
    __builtin_amdgcn_sched_barrier(0);

    // odd step: compute t=tt+1 from buf1
    compute(1);
    __builtin_amdgcn_s_barrier();
    __builtin_amdgcn_sched_barrier(0);
    write_w(Wp);                             // W(t+2)
    Wp = load_w(tt + 3);
    stage_x(1, tt + 3);
    asm volatile("s_waitcnt vmcnt(16)" ::: "memory");
    asm volatile("s_waitcnt lgkmcnt(0)" ::: "memory");
    __builtin_amdgcn_s_barrier();
    __builtin_amdgcn_sched_barrier(0);
  }

  // ---------------- tail: t=14, t=15 ----------------
  compute(0);                                // t=14
  __builtin_amdgcn_s_barrier();
  __builtin_amdgcn_sched_barrier(0);
  write_w(Wp);                               // W(15)
  asm volatile("s_waitcnt vmcnt(0)" ::: "memory");    // x(15) complete (drain OK in tail)
  asm volatile("s_waitcnt lgkmcnt(0)" ::: "memory");
  __builtin_amdgcn_s_barrier();
  __builtin_amdgcn_sched_barrier(0);
  compute(1);                                // t=15

  // ---- epilogue: interleaved (re, im) float2 stores, coalesced in h ----
#pragma unroll
  for (int mi = 0; mi < 4; ++mi) {
#pragma unroll
    for (int r = 0; r < 4; ++r) {
      const int m = m0 + wm + mi * 16 + h4 * 4 + r;  // C/D: row = (lane>>4)*4 + reg
#pragma unroll
      for (int ni = 0; ni < 4; ++ni) {
        const int h = n0 + wn + ni * 16 + l16;       // C/D: col = lane & 15
        float2 v;
        v.x = acc_re[mi][ni][r];
        v.y = acc_im[mi][ni][r];
        *(float2*)(out + ((size_t)m * NDIM + h) * 2) = v;
      }
    }
  }
}

extern "C" void kernel_launch(void* const* d_in, const int* in_sizes, int n_in,
                              void* d_out, int out_size, void* d_ws, size_t ws_size,
                              hipStream_t stream) {
  const float* xr  = (const float*)d_in[0];
  const float* xi  = (const float*)d_in[1];
  const float* wre = (const float*)d_in[2];
  const float* wim = (const float*)d_in[3];
  float* out = (float*)d_out;

  dim3 grid(1024);  // (m-tiles 256) x (n-tiles 4), XCD-swizzled inside kernel
  dim3 block(256);
  dft_cgemm_kernel<<<grid, block, 0, stream>>>(xr, xi, wre, wim, out);
}

// Round 2
// 370.490 us; speedup vs baseline: 1.2268x; 1.2268x over previous
//
#include <hip/hip_runtime.h>

typedef __bf16 bf16_t;
typedef __bf16 bf16x8 __attribute__((ext_vector_type(8)));
typedef float f32x4 __attribute__((ext_vector_type(4)));
typedef unsigned int u32x4 __attribute__((ext_vector_type(4)));

#define KDIM 512
#define NDIM 512
#define BM 128
#define BN 128
#define BK 32
#define NSTEP (KDIM / BK)  // 16

// async 16B global->LDS. LDS dest must be wave-uniform base; HW scatters lane*16.
__device__ __forceinline__ void gld_lds16(const float* g, float* lds_uniform) {
  __builtin_amdgcn_global_load_lds(
      (const __attribute__((address_space(1))) void*)g,
      (__attribute__((address_space(3))) void*)lds_uniform, 16, 0, 0);
}

__device__ __forceinline__ bf16x8 neg8(bf16x8 v) {
  union { bf16x8 b; u32x4 u; } x;
  x.b = v;
  x.u = x.u ^ 0x80008000u;  // flip bf16 sign bits (packed)
  return x.b;
}

// Read one A fragment (8 fp32 along k) from the granule-swizzled fp32 LDS tile
// and convert to bf16x8. Tile layout: slot(row, g') holds global granule
// g = g' ^ (row & 7); granule = 4 floats = 16 B. 2-way bank alias only (free).
__device__ __forceinline__ bf16x8 afrag(const float* ldsx, int r, int h4) {
  const int base = r * 8;
  const int sw = r & 7;
  const float4 a = *(const float4*)(ldsx + 4 * (base + ((2 * h4) ^ sw)));
  const float4 b = *(const float4*)(ldsx + 4 * (base + ((2 * h4 + 1) ^ sw)));
  bf16x8 f;
  f[0] = (__bf16)a.x; f[1] = (__bf16)a.y; f[2] = (__bf16)a.z; f[3] = (__bf16)a.w;
  f[4] = (__bf16)b.x; f[5] = (__bf16)b.y; f[6] = (__bf16)b.z; f[7] = (__bf16)b.w;
  return f;
}

__device__ __forceinline__ bf16x8 pack8(float4 a, float4 b) {
  bf16x8 f;
  f[0] = (__bf16)a.x; f[1] = (__bf16)a.y; f[2] = (__bf16)a.z; f[3] = (__bf16)a.w;
  f[4] = (__bf16)b.x; f[5] = (__bf16)b.y; f[6] = (__bf16)b.z; f[7] = (__bf16)b.w;
  return f;
}

struct Wregs { float4 r0, r1, i0, i1, r2, r3, i2, i3; };  // 32 VGPRs

// Minimum 2-phase pipeline (T3 recipe), compiler-managed waits ONLY:
//   - x: double-buffered LDS; DMAs for tile t+1 issued BEFORE tile t's MFMAs.
//     The only vmcnt(0) drain is the __syncthreads() AFTER the MFMAs, so the
//     DMAs hide under the ds_read+MFMA phase.
//   - W: single LDS buffer; global->reg loads issued with the x DMAs (overlap
//     MFMA), cvt+ds_write after the post-MFMA barrier. Second barrier only
//     pays an lgkm drain (vmem already drained by the first).
// Prefetch distance is exactly 1 (keeps same-XCD panel-sharing blocks paced
// together -> L2/LLC reuse like the baseline; round-1's t+2 distance thrashed).
__global__ __launch_bounds__(256, 2) void dft_cgemm_kernel(
    const float* __restrict__ xr, const float* __restrict__ xi,
    const float* __restrict__ wre, const float* __restrict__ wim,
    float* __restrict__ out) {
  __shared__ __align__(16) float  lds_x[2][2][BM * BK];  // [kbuf][re/im], 64 KB
  __shared__ __align__(16) bf16_t lds_w[2][BN * BK];     // [re/im], 16 KB, fragment-ordered
  // total 80 KB -> 2 blocks/CU (LDS-bound), same occupancy as baseline

  const int t = threadIdx.x;
  const int lane = t & 63;
  const int wv = t >> 6;  // wave 0..3

  // XCD-aware swizzle: xcd = b&7 owns m-tiles [32*xcd, 32*xcd+32) x all 4 n-tiles,
  // so each XCD's L2 fetches a given x-row range exactly once.
  const int b = blockIdx.x;  // 0..1023
  const int xcd = b & 7;
  const int sidx = b >> 3;   // 0..127
  const int m0 = (xcd * 32 + (sidx >> 2)) * BM;
  const int n0 = (sidx & 3) * BN;

  // wave tile: 64x64; 2x2 wave grid over the 128x128 block tile
  const int wm = (wv >> 1) * 64;
  const int wn = (wv & 1) * 64;
  const int l16 = lane & 15;  // A row / B row (n) within 16-frag
  const int h4 = lane >> 4;   // k-granule selector (0..3)
  const int wt15 = t & 15;
  const int wg = (t >> 4) & 3;

  f32x4 acc_re[4][4], acc_im[4][4];
#pragma unroll
  for (int i = 0; i < 4; ++i)
#pragma unroll
    for (int j = 0; j < 4; ++j) {
      acc_re[i][j] = (f32x4){0.f, 0.f, 0.f, 0.f};
      acc_im[i][j] = (f32x4){0.f, 0.f, 0.f, 0.f};
    }

  // ---- stage x (fp32, async DMA, granule-swizzled global addresses) ----
  auto stage_x = [&](int buf, int step) {
    const int k0 = step * BK;
#pragma unroll
    for (int it = 0; it < 4; ++it) {
      const int S = it * 256 + t;         // granule slot 0..1023
      const int row = S >> 3;
      const int g = (S & 7) ^ (row & 7);  // global granule for this slot
      const size_t goff = (size_t)(m0 + row) * KDIM + k0 + g * 4;
      float* dr = &lds_x[buf][0][0] + 4 * (it * 256 + wv * 64);  // wave-uniform base
      float* di = &lds_x[buf][1][0] + 4 * (it * 256 + wv * 64);
      gld_lds16(xr + goff, dr);
      gld_lds16(xi + goff, di);
    }
  };

  // ---- W prefetch: 8 float4 global loads into registers ----
  auto load_w = [&](int step) {
    Wregs W;
    const int k0 = step * BK;
    const int row0 = wv * 16 + wt15;  // rows 0..63   (== baseline c=0)
    const float* gr0 = wre + (size_t)(n0 + row0) * KDIM + k0 + wg * 8;
    const float* gi0 = wim + (size_t)(n0 + row0) * KDIM + k0 + wg * 8;
    W.r0 = ((const float4*)gr0)[0]; W.r1 = ((const float4*)gr0)[1];
    W.i0 = ((const float4*)gi0)[0]; W.i1 = ((const float4*)gi0)[1];
    const int row1 = 64 + wv * 16 + wt15;  // rows 64..127 (== baseline c=1)
    const float* gr1 = wre + (size_t)(n0 + row1) * KDIM + k0 + wg * 8;
    const float* gi1 = wim + (size_t)(n0 + row1) * KDIM + k0 + wg * 8;
    W.r2 = ((const float4*)gr1)[0]; W.r3 = ((const float4*)gr1)[1];
    W.i2 = ((const float4*)gi1)[0]; W.i3 = ((const float4*)gi1)[1];
    return W;
  };

  // ---- cvt + ds_write W into fragment-ordered LDS (wave-contiguous slots) ----
  auto write_w = [&](const Wregs& W) {
    *(bf16x8*)(&lds_w[0][0] + (size_t)t * 8)         = pack8(W.r0, W.r1);
    *(bf16x8*)(&lds_w[1][0] + (size_t)t * 8)         = pack8(W.i0, W.i1);
    *(bf16x8*)(&lds_w[0][0] + (size_t)(256 + t) * 8) = pack8(W.r2, W.r3);
    *(bf16x8*)(&lds_w[1][0] + (size_t)(256 + t) * 8) = pack8(W.i2, W.i3);
  };

  // ---------------- prologue ----------------
  Wregs Wn = load_w(0);  // W(0) loads issued first (oldest)
  stage_x(0, 0);         // then x(0) DMAs
  write_w(Wn);           // compiler waits for W(0) only; x(0) keeps flying
  __syncthreads();       // drains x(0) DMA + W ds_write; tile 0 ready

  // ---------------- main loop ----------------
#pragma unroll 1
  for (int tt = 0; tt < NSTEP; ++tt) {
    const int cur = tt & 1;
    const float* ldsxr = &lds_x[cur][0][0];
    const float* ldsxi = &lds_x[cur][1][0];

    // issue next tile's loads FIRST (overlap with ds_read + MFMA below)
    if (tt + 1 < NSTEP) {
      stage_x(cur ^ 1, tt + 1);  // x(t+1) DMA into the other buffer
      Wn = load_w(tt + 1);       // W(t+1) -> regs
    }

    // ---- fragments ----
    bf16x8 ar[4], ai[4], br[4], bi[4], nbi[4];
#pragma unroll
    for (int mi = 0; mi < 4; ++mi) {
      const int r = wm + mi * 16 + l16;
      ar[mi] = afrag(ldsxr, r, h4);
      ai[mi] = afrag(ldsxi, r, h4);
    }
#pragma unroll
    for (int ni = 0; ni < 4; ++ni) {
      const int slot = ((wn >> 4) + ni) * 64 + h4 * 16 + l16;
      br[ni] = *(const bf16x8*)(&lds_w[0][0] + slot * 8);
      bi[ni] = *(const bf16x8*)(&lds_w[1][0] + slot * 8);
      nbi[ni] = neg8(bi[ni]);
    }

    // ---- 4 MFMA streams: re += xr*wr - xi*wi ; im += xr*wi + xi*wr ----
#pragma unroll
    for (int mi = 0; mi < 4; ++mi) {
#pragma unroll
      for (int ni = 0; ni < 4; ++ni) {
        acc_re[mi][ni] = __builtin_amdgcn_mfma_f32_16x16x32_bf16(ar[mi], br[ni], acc_re[mi][ni], 0, 0, 0);
        acc_im[mi][ni] = __builtin_amdgcn_mfma_f32_16x16x32_bf16(ar[mi], bi[ni], acc_im[mi][ni], 0, 0, 0);
        acc_re[mi][ni] = __builtin_amdgcn_mfma_f32_16x16x32_bf16(ai[mi], nbi[ni], acc_re[mi][ni], 0, 0, 0);
        acc_im[mi][ni] = __builtin_amdgcn_mfma_f32_16x16x32_bf16(ai[mi], br[ni], acc_im[mi][ni], 0, 0, 0);
      }
    }

    __syncthreads();  // everyone done reading lds_w / lds_x[cur]; drains x(t+1)+W(t+1)
    if (tt + 1 < NSTEP) {
      write_w(Wn);     // W(t+1) -> lds_w (vmem already drained; only cvt+ds_write)
      __syncthreads(); // cheap: only lgkm drain, no vmem outstanding
    }
  }

  // ---- epilogue: interleaved (re, im) float2 stores, coalesced in h ----
#pragma unroll
  for (int mi = 0; mi < 4; ++mi) {
#pragma unroll
    for (int r = 0; r < 4; ++r) {
      const int m = m0 + wm + mi * 16 + h4 * 4 + r;  // C/D: row = (lane>>4)*4 + reg
#pragma unroll
      for (int ni = 0; ni < 4; ++ni) {
        const int h = n0 + wn + ni * 16 + l16;       // C/D: col = lane & 15
        float2 v;
        v.x = acc_re[mi][ni][r];
        v.y = acc_im[mi][ni][r];
        *(float2*)(out + ((size_t)m * NDIM + h) * 2) = v;
      }
    }
  }
}

extern "C" void kernel_launch(void* const* d_in, const int* in_sizes, int n_in,
                              void* d_out, int out_size, void* d_ws, size_t ws_size,
                              hipStream_t stream) {
  const float* xr  = (const float*)d_in[0];
  const float* xi  = (const float*)d_in[1];
  const float* wre = (const float*)d_in[2];
  const float* wim = (const float*)d_in[3];
  float* out = (float*)d_out;

  dim3 grid(1024);  // (m-tiles 256) x (n-tiles 4), XCD-swizzled inside kernel
  dim3 block(256);
  dft_cgemm_kernel<<<grid, block, 0, stream>>>(xr, xi, wre, wim, out);
}